// Round 1
// baseline (23.849 us; speedup 1.0000x reference)
//
#include <hip/hip_runtime.h>

constexpr int Q    = 20;
constexpr int EMB  = 64;
constexpr int Bsz  = 16, H = 48, W = 48;
constexpr int HW   = H * W;          // 2304
constexpr int NPIX = Bsz * HW;       // 36864
constexpr int BLOCK = 256;

__global__ __launch_bounds__(BLOCK)
void act_pre_kernel(const int* __restrict__ unit,
                    const int* __restrict__ atp,  const int* __restrict__ dirp,
                    const int* __restrict__ resp, const int* __restrict__ repp,
                    const float* __restrict__ amtp, const float* __restrict__ np_,
                    const float* __restrict__ Ttab, const float* __restrict__ Dtab,
                    const float* __restrict__ Rtab, const float* __restrict__ Ptab,
                    const float* __restrict__ w1p,  const float* __restrict__ b1p,
                    const float* __restrict__ w2p,  const float* __restrict__ b2p,
                    float* __restrict__ out)
{
    // Combined scaled table: rows 0-5 = w2[0]*type, 6-10 = w2[1]*dir,
    // 11-15 = w2[2]*res, 16-17 = w2[4]*repeat.
    __shared__ float sc[18][EMB];
    __shared__ float sw1[Q];
    __shared__ float sconst[3];   // w2[3], w2[5], b1*sum(w2)+b2

    const int tid = threadIdx.x;
    for (int i = tid; i < 18 * EMB; i += BLOCK) {
        const int row = i >> 6, e = i & 63;
        float v, s;
        if (row < 6)       { v = Ttab[row * EMB + e];        s = w2p[0]; }
        else if (row < 11) { v = Dtab[(row - 6) * EMB + e];  s = w2p[1]; }
        else if (row < 16) { v = Rtab[(row - 11) * EMB + e]; s = w2p[2]; }
        else               { v = Ptab[(row - 16) * EMB + e]; s = w2p[4]; }
        sc[row][e] = v * s;
    }
    if (tid < Q) sw1[tid] = w1p[tid];
    if (tid == 0) {
        sconst[0] = w2p[3];
        sconst[1] = w2p[5];
        const float sumw2 = w2p[0] + w2p[1] + w2p[2] + w2p[3] + w2p[4] + w2p[5];
        sconst[2] = b1p[0] * sumw2 + b2p[0];
    }
    __syncthreads();

    const int pix = blockIdx.x * BLOCK + tid;   // grid is exact (144*256 = 36864)

    // --- per-pixel coefficient accumulation over Q (all static indexing) ---
    float cT[6] = {}, cD[5] = {}, cR[5] = {};
    float repAcc = 0.f, amtAcc = 0.f, nAcc = 0.f, sumw = 0.f;

    const int4*   a4 = reinterpret_cast<const int4*>(atp  + pix * Q);
    const int4*   d4 = reinterpret_cast<const int4*>(dirp + pix * Q);
    const int4*   r4 = reinterpret_cast<const int4*>(resp + pix * Q);
    const int4*   p4 = reinterpret_cast<const int4*>(repp + pix * Q);
    const float4* m4 = reinterpret_cast<const float4*>(amtp + pix * Q);
    const float4* n4 = reinterpret_cast<const float4*>(np_  + pix * Q);

    #pragma unroll
    for (int v = 0; v < Q / 4; ++v) {
        const int4   a = a4[v], d = d4[v], r = r4[v], p = p4[v];
        const float4 m = m4[v], nn = n4[v];
        const int   ai[4] = {a.x, a.y, a.z, a.w};
        const int   di[4] = {d.x, d.y, d.z, d.w};
        const int   ri[4] = {r.x, r.y, r.z, r.w};
        const int   pi[4] = {p.x, p.y, p.z, p.w};
        const float mf[4] = {m.x, m.y, m.z, m.w};
        const float nf[4] = {nn.x, nn.y, nn.z, nn.w};
        #pragma unroll
        for (int j = 0; j < 4; ++j) {
            const float wq = sw1[v * 4 + j];
            sumw += wq;
            #pragma unroll
            for (int t = 0; t < 6; ++t) cT[t] += (ai[j] == t) ? wq : 0.f;
            #pragma unroll
            for (int t = 0; t < 5; ++t) cD[t] += (di[j] == t) ? wq : 0.f;
            #pragma unroll
            for (int t = 0; t < 5; ++t) cR[t] += (ri[j] == t) ? wq : 0.f;
            repAcc += (pi[j] != 0) ? wq : 0.f;
            amtAcc += wq * mf[j];
            nAcc   += wq * nf[j];
        }
    }

    const float scalar = sconst[0] * amtAcc + sconst[1] * nAcc + sconst[2];
    const float cP1 = repAcc;
    const float cP0 = sumw - repAcc;
    const float ind = (unit[pix] != 0) ? 1.f : 0.f;

    const int b  = pix / HW;
    const int hw = pix - b * HW;
    float* outp = out + b * (EMB * HW) + hw;

    // --- combine: c[e] = scalar + sum_k coef[k]*sc[k][e]; LDS reads broadcast ---
    #pragma unroll
    for (int e0 = 0; e0 < EMB; e0 += 4) {
        float va[4];
        #pragma unroll
        for (int j = 0; j < 4; ++j) va[j] = scalar;
        #pragma unroll
        for (int k = 0; k < 18; ++k) {
            const float ck = (k < 6)  ? cT[k]
                           : (k < 11) ? cD[k - 6]
                           : (k < 16) ? cR[k - 11]
                           : (k == 16) ? cP0 : cP1;
            const float4 sv = *reinterpret_cast<const float4*>(&sc[k][e0]);
            va[0] += ck * sv.x;
            va[1] += ck * sv.y;
            va[2] += ck * sv.z;
            va[3] += ck * sv.w;
        }
        #pragma unroll
        for (int j = 0; j < 4; ++j) {
            float vv = va[j];
            vv = (vv >= 0.f) ? vv : 0.01f * vv;   // LeakyReLU(0.01)
            outp[(e0 + j) * HW] = vv * ind;
        }
    }
}

extern "C" void kernel_launch(void* const* d_in, const int* in_sizes, int n_in,
                              void* d_out, int out_size, void* d_ws, size_t ws_size,
                              hipStream_t stream) {
    const int*   unit = (const int*)  d_in[0];
    const int*   atp  = (const int*)  d_in[1];
    const int*   dirp = (const int*)  d_in[2];
    const int*   resp = (const int*)  d_in[3];
    const int*   repp = (const int*)  d_in[4];
    const float* amtp = (const float*)d_in[5];
    const float* np_  = (const float*)d_in[6];
    const float* Ttab = (const float*)d_in[7];
    const float* Dtab = (const float*)d_in[8];
    const float* Rtab = (const float*)d_in[9];
    const float* Ptab = (const float*)d_in[10];
    const float* w1p  = (const float*)d_in[11];
    const float* b1p  = (const float*)d_in[12];
    const float* w2p  = (const float*)d_in[13];
    const float* b2p  = (const float*)d_in[14];
    float* out = (float*)d_out;

    act_pre_kernel<<<NPIX / BLOCK, BLOCK, 0, stream>>>(
        unit, atp, dirp, resp, repp, amtp, np_,
        Ttab, Dtab, Rtab, Ptab, w1p, b1p, w2p, b2p, out);
}

// Round 2
// 14.249 us; speedup vs baseline: 1.6737x; 1.6737x over previous
//
#include <hip/hip_runtime.h>

constexpr int Q    = 20;
constexpr int EMB  = 64;
constexpr int Bsz  = 16, H = 48, W = 48;
constexpr int HW   = H * W;          // 2304
constexpr int NPIX = Bsz * HW;       // 36864
constexpr int BLOCK = 256;
constexpr int TPP   = 4;             // threads per pixel
constexpr int PIXPB = BLOCK / TPP;   // 64 pixels per block
constexpr int NBLK  = NPIX / PIXPB;  // 576 blocks

__global__ __launch_bounds__(BLOCK)
void act_pre_kernel(const int* __restrict__ unit,
                    const int* __restrict__ atp,  const int* __restrict__ dirp,
                    const int* __restrict__ resp, const int* __restrict__ repp,
                    const float* __restrict__ amtp, const float* __restrict__ np_,
                    const float* __restrict__ Ttab, const float* __restrict__ Dtab,
                    const float* __restrict__ Rtab, const float* __restrict__ Ptab,
                    const float* __restrict__ w1p,  const float* __restrict__ b1p,
                    const float* __restrict__ w2p,  const float* __restrict__ b2p,
                    float* __restrict__ out)
{
    // Combined scaled table: rows 0-5 = w2[0]*type, 6-10 = w2[1]*dir,
    // 11-15 = w2[2]*res, 16-17 = w2[4]*repeat.
    __shared__ float sc[18][EMB];
    __shared__ float sw1[Q];
    __shared__ float sconst[4];   // w2[3], w2[5], b1*sum(w2)+b2, sum(w1)

    const int tid = threadIdx.x;
    for (int i = tid; i < 18 * EMB; i += BLOCK) {
        const int row = i >> 6, e = i & 63;
        float v, s;
        if (row < 6)       { v = Ttab[row * EMB + e];        s = w2p[0]; }
        else if (row < 11) { v = Dtab[(row - 6) * EMB + e];  s = w2p[1]; }
        else if (row < 16) { v = Rtab[(row - 11) * EMB + e]; s = w2p[2]; }
        else               { v = Ptab[(row - 16) * EMB + e]; s = w2p[4]; }
        sc[row][e] = v * s;
    }
    if (tid < Q) sw1[tid] = w1p[tid];
    if (tid == 0) {
        sconst[0] = w2p[3];
        sconst[1] = w2p[5];
        const float sumw2 = w2p[0] + w2p[1] + w2p[2] + w2p[3] + w2p[4] + w2p[5];
        sconst[2] = b1p[0] * sumw2 + b2p[0];
        float sw = 0.f;
        for (int q = 0; q < Q; ++q) sw += w1p[q];
        sconst[3] = sw;
    }
    __syncthreads();

    const int pIB = tid >> 2;          // pixel within block
    const int t   = tid & 3;           // sub-thread within pixel
    const int pix = blockIdx.x * PIXPB + pIB;

    // --- thread t owns q in [4t, 4t+4) (vector) and q = 16+t (scalar) ---
    const int base = pix * Q + t * 4;
    const int4   av = *reinterpret_cast<const int4*>(atp  + base);
    const int4   dv = *reinterpret_cast<const int4*>(dirp + base);
    const int4   rv = *reinterpret_cast<const int4*>(resp + base);
    const int4   pv = *reinterpret_cast<const int4*>(repp + base);
    const float4 mv = *reinterpret_cast<const float4*>(amtp + base);
    const float4 nv = *reinterpret_cast<const float4*>(np_  + base);
    const int tail  = pix * Q + 16 + t;
    const int   as = atp[tail],  ds = dirp[tail], rs = resp[tail], ps = repp[tail];
    const float ms = amtp[tail], ns = np_[tail];

    const int   ai[5] = {av.x, av.y, av.z, av.w, as};
    const int   di[5] = {dv.x, dv.y, dv.z, dv.w, ds};
    const int   ri[5] = {rv.x, rv.y, rv.z, rv.w, rs};
    const int   pi[5] = {pv.x, pv.y, pv.z, pv.w, ps};
    const float mf[5] = {mv.x, mv.y, mv.z, mv.w, ms};
    const float nf[5] = {nv.x, nv.y, nv.z, nv.w, ns};

    float cT[6] = {}, cD[5] = {}, cR[5] = {};
    float repAcc = 0.f, amtAcc = 0.f, nAcc = 0.f;

    #pragma unroll
    for (int j = 0; j < 5; ++j) {
        const int q = (j < 4) ? (t * 4 + j) : (16 + t);
        const float wq = sw1[q];
        #pragma unroll
        for (int k = 0; k < 6; ++k) cT[k] += (ai[j] == k) ? wq : 0.f;
        #pragma unroll
        for (int k = 0; k < 5; ++k) cD[k] += (di[j] == k) ? wq : 0.f;
        #pragma unroll
        for (int k = 0; k < 5; ++k) cR[k] += (ri[j] == k) ? wq : 0.f;
        repAcc += (pi[j] != 0) ? wq : 0.f;
        amtAcc += wq * mf[j];
        nAcc   += wq * nf[j];
    }

    // --- butterfly reduce across the 4 threads of this pixel (lanes 4p..4p+3) ---
    #define RED4(x) { x += __shfl_xor(x, 1); x += __shfl_xor(x, 2); }
    #pragma unroll
    for (int k = 0; k < 6; ++k) RED4(cT[k]);
    #pragma unroll
    for (int k = 0; k < 5; ++k) RED4(cD[k]);
    #pragma unroll
    for (int k = 0; k < 5; ++k) RED4(cR[k]);
    RED4(repAcc); RED4(amtAcc); RED4(nAcc);
    #undef RED4

    const float scalar = sconst[0] * amtAcc + sconst[1] * nAcc + sconst[2];
    const float ind = (unit[pix] != 0) ? 1.f : 0.f;

    float coef[18];
    #pragma unroll
    for (int k = 0; k < 6; ++k) coef[k] = cT[k];
    #pragma unroll
    for (int k = 0; k < 5; ++k) coef[6 + k] = cD[k];
    #pragma unroll
    for (int k = 0; k < 5; ++k) coef[11 + k] = cR[k];
    coef[16] = sconst[3] - repAcc;   // cP0 = sum(w1) - rep
    coef[17] = repAcc;               // cP1

    const int b  = pix / HW;
    const int hw = pix - b * HW;
    float* outp = out + b * (EMB * HW) + hw;

    // --- each thread computes 16 of the 64 channels: e in [16t, 16t+16) ---
    #pragma unroll
    for (int i = 0; i < 4; ++i) {
        const int e0 = t * 16 + i * 4;
        float va0 = scalar, va1 = scalar, va2 = scalar, va3 = scalar;
        #pragma unroll
        for (int k = 0; k < 18; ++k) {
            const float4 sv = *reinterpret_cast<const float4*>(&sc[k][e0]);
            va0 += coef[k] * sv.x;
            va1 += coef[k] * sv.y;
            va2 += coef[k] * sv.z;
            va3 += coef[k] * sv.w;
        }
        va0 = ((va0 >= 0.f) ? va0 : 0.01f * va0) * ind;
        va1 = ((va1 >= 0.f) ? va1 : 0.01f * va1) * ind;
        va2 = ((va2 >= 0.f) ? va2 : 0.01f * va2) * ind;
        va3 = ((va3 >= 0.f) ? va3 : 0.01f * va3) * ind;
        outp[(e0 + 0) * HW] = va0;
        outp[(e0 + 1) * HW] = va1;
        outp[(e0 + 2) * HW] = va2;
        outp[(e0 + 3) * HW] = va3;
    }
}

extern "C" void kernel_launch(void* const* d_in, const int* in_sizes, int n_in,
                              void* d_out, int out_size, void* d_ws, size_t ws_size,
                              hipStream_t stream) {
    const int*   unit = (const int*)  d_in[0];
    const int*   atp  = (const int*)  d_in[1];
    const int*   dirp = (const int*)  d_in[2];
    const int*   resp = (const int*)  d_in[3];
    const int*   repp = (const int*)  d_in[4];
    const float* amtp = (const float*)d_in[5];
    const float* np_  = (const float*)d_in[6];
    const float* Ttab = (const float*)d_in[7];
    const float* Dtab = (const float*)d_in[8];
    const float* Rtab = (const float*)d_in[9];
    const float* Ptab = (const float*)d_in[10];
    const float* w1p  = (const float*)d_in[11];
    const float* b1p  = (const float*)d_in[12];
    const float* w2p  = (const float*)d_in[13];
    const float* b2p  = (const float*)d_in[14];
    float* out = (float*)d_out;

    act_pre_kernel<<<NBLK, BLOCK, 0, stream>>>(
        unit, atp, dirp, resp, repp, amtp, np_,
        Ttab, Dtab, Rtab, Ptab, w1p, b1p, w2p, b2p, out);
}